// Round 3
// baseline (561.491 us; speedup 1.0000x reference)
//
#include <hip/hip_runtime.h>

typedef short short8 __attribute__((ext_vector_type(8)));
typedef float f32x4 __attribute__((ext_vector_type(4)));
typedef unsigned short ushort;

#define MFMA(a, b, c) __builtin_amdgcn_mfma_f32_16x16x32_bf16(a, b, c, 0, 0, 0)

__device__ __forceinline__ ushort f2bf(float x) {
    unsigned u = __float_as_uint(x);
    u = (u + 0x7FFFu + ((u >> 16) & 1u)) >> 16;   // RNE
    return (ushort)u;
}
__device__ __forceinline__ float bf2f(ushort u) {
    return __uint_as_float(((unsigned)u) << 16);
}

// ======================= NEW PIPELINE (needs big ws) =======================
// ws element (ushort) offsets
#define WS_Q   0         // 18 frags (kt*6+nt)  : Wq^T pre-scaled x0.25
#define WS_KV  9216      // 72 frags (kt6*12+nt): [Wk|Wv] combined, cout 0..191
#define WS_O   46080     // 18 frags (kt*6+mt)  : Wo^T as A-operand (m=cout,k=c)
#define WS_BT  55296     // bias table bf16 [1350]
#define WS_BIG 56648     // 16B-aligned start of big buffers
#define QBUF_OFF  WS_BIG                    // [262144][96]  bf16
#define KVBUF_OFF (WS_BIG + 25165824)       // [262144][192] bf16 (k|v)
#define ABUF_OFF  (KVBUF_OFF + 50331648)    // [262144][96]  bf16 attn-out
#define NEED_BYTES ((size_t)(ABUF_OFF + 25165824) * 2)

__global__ void prep_w(const float* __restrict__ Wq, const float* __restrict__ Wk,
                       const float* __restrict__ Wv, const float* __restrict__ Wo,
                       const float* __restrict__ btab, ushort* __restrict__ ws) {
    int idx = blockIdx.x * 256 + threadIdx.x;
    if (idx < WS_KV) {                      // Q frags, B-operand: n=l15=cout, k=quad*8+j
        int f = idx >> 9, w = idx & 511, lane = w >> 3, j = w & 7;
        int kt = f / 6, nt = f % 6;
        int cout = nt * 16 + (lane & 15), c = kt * 32 + (lane >> 4) * 8 + j;
        ws[idx] = f2bf(Wq[c * 96 + cout] * 0.25f);   // fold softmax scale 2^-2
    } else if (idx < WS_O) {                // KV frags
        int t = idx - WS_KV; int f = t >> 9, w = t & 511, lane = w >> 3, j = w & 7;
        int kt6 = f / 12, nt = f % 12;
        int cout = nt * 16 + (lane & 15), c = kt6 * 32 + (lane >> 4) * 8 + j;
        float v = (cout < 96) ? Wk[c * 96 + cout] : Wv[c * 96 + (cout - 96)];
        ws[idx] = f2bf(v);
    } else if (idx < WS_BT) {               // O frags, A-operand: m=l15=cout, k=c
        int t = idx - WS_O; int f = t >> 9, w = t & 511, lane = w >> 3, j = w & 7;
        int kt = f / 6, mt = f % 6;
        int m = mt * 16 + (lane & 15), k = kt * 32 + (lane >> 4) * 8 + j;
        ws[idx] = f2bf(Wo[k * 96 + m]);
    } else if (idx < WS_BIG) {
        if (idx < WS_BT + 1350) ws[idx] = f2bf(btab[idx - WS_BT]);
    }
}

// ---- K2: qkv projection GEMM over contiguous 64-token tiles ----
// blocks 0..4095: q-proj (b = blk>>10, tok tile);  4096..8191: kv-proj
__global__ __launch_bounds__(256, 4) void k2_proj(
    const float* __restrict__ xq, const float* __restrict__ xkv,
    const float* __restrict__ bq, const float* __restrict__ bk,
    const float* __restrict__ bv, const ushort* __restrict__ ws,
    ushort* __restrict__ qbuf, ushort* __restrict__ kvbuf)
{
    __shared__ ushort At[64 * 104];   // [tok][c] bf16, stride 104 (16B-aligned rows)
    const int tid = threadIdx.x;
    const int wave = tid >> 6, lane = tid & 63, l15 = lane & 15, quad = lane >> 4;
    const bool isQ = blockIdx.x < 4096;
    const int g = isQ ? blockIdx.x : blockIdx.x - 4096;
    const int b = g >> 10, tok0 = (g & 1023) * 64;
    const int arow = (wave * 16 + l15) * 104 + quad * 8;
    const int trow = tok0 + wave * 16 + quad * 4;           // first output token row

    if (isQ) {
        const float* src = xq + (size_t)b * 96 * 65536;
        #pragma unroll 4
        for (int p = 0; p < 24; ++p) {                       // coalesced: 64 consec toks
            int c = p * 4 + wave;
            At[lane * 104 + c] = f2bf(src[c * 65536 + tok0 + lane]);
        }
        __syncthreads();
        f32x4 acc[6];
        #pragma unroll
        for (int n = 0; n < 6; ++n) acc[n] = {};
        #pragma unroll
        for (int kt = 0; kt < 3; ++kt) {
            short8 a = *(const short8*)(At + arow + kt * 32);
            #pragma unroll
            for (int nt = 0; nt < 6; ++nt) {
                short8 w8 = *(const short8*)(ws + WS_Q + ((kt * 6 + nt) * 64 + lane) * 8);
                acc[nt] = MFMA(a, w8, acc[nt]);
            }
        }
        ushort* dst = qbuf + ((size_t)b * 65536 + trow) * 96;
        #pragma unroll
        for (int nt = 0; nt < 6; ++nt) {
            float bias = bq[nt * 16 + l15] * 0.25f;
            #pragma unroll
            for (int r = 0; r < 4; ++r)
                dst[r * 96 + nt * 16 + l15] = f2bf(acc[nt][r] + bias);
        }
    } else {
        const float* src = xkv + (size_t)b * 192 * 65536;
        f32x4 acc[12];
        #pragma unroll
        for (int n = 0; n < 12; ++n) acc[n] = {};
        for (int half = 0; half < 2; ++half) {
            if (half) __syncthreads();                       // At reads done
            const float* s2 = src + half * 96 * 65536;
            #pragma unroll 4
            for (int p = 0; p < 24; ++p) {
                int c = p * 4 + wave;
                At[lane * 104 + c] = f2bf(s2[c * 65536 + tok0 + lane]);
            }
            __syncthreads();
            #pragma unroll
            for (int kt = 0; kt < 3; ++kt) {
                short8 a = *(const short8*)(At + arow + kt * 32);
                int kt6 = half * 3 + kt;
                #pragma unroll
                for (int nt = 0; nt < 12; ++nt) {
                    short8 w8 = *(const short8*)(ws + WS_KV + ((kt6 * 12 + nt) * 64 + lane) * 8);
                    acc[nt] = MFMA(a, w8, acc[nt]);
                }
            }
        }
        ushort* dst = kvbuf + ((size_t)b * 65536 + trow) * 192;
        #pragma unroll
        for (int nt = 0; nt < 12; ++nt) {
            int cout = nt * 16 + l15;
            float bias = (cout < 96) ? bk[cout] : bv[cout - 96];
            #pragma unroll
            for (int r = 0; r < 4; ++r)
                dst[r * 192 + cout] = f2bf(acc[nt][r] + bias);
        }
    }
}

// ---- K3: window attention (q,k direct-from-global frags; v via LDS transpose) ----
#define K3_VT 0          // [96 d][72] ushort = 13824 B
#define K3_PS 13824      // ps [4][16][72] (9216B) overlaid by obuf [64][96] (12288B)
#define K3_BIAS 26112    // 1350 ushort = 2700 B
#define K3_LDS 28812

__global__ __launch_bounds__(256, 4) void k3_attn(
    const ushort* __restrict__ ws, const ushort* __restrict__ qbuf,
    const ushort* __restrict__ kvbuf, ushort* __restrict__ abuf)
{
    __shared__ __align__(16) char smem[K3_LDS];
    ushort* vt    = (ushort*)smem;                        // [d][tok] stride 72
    ushort* biasl = (ushort*)(smem + K3_BIAS);
    const int tid = threadIdx.x;
    const int wave = tid >> 6, lane = tid & 63, l15 = lane & 15, quad = lane >> 4;
    const int wid = blockIdx.x;
    const int b = wid >> 10, wh = (wid >> 5) & 31, ww = wid & 31;
    const int wb = b * 65536 + (wh * 8) * 256 + ww * 8;   // window base global token

    for (int i = tid; i < 1350; i += 256) biasl[i] = ws[WS_BT + i];
    {   // stage v -> vt[d][tok]
        int tok = tid >> 2, cc = tid & 3;
        int tg = wb + (tok >> 3) * 256 + (tok & 7);
        const ushort* vrow = kvbuf + (size_t)tg * 192 + 96;
        #pragma unroll
        for (int rd = 0; rd < 3; ++rd) {
            int vd0 = (rd * 4 + cc) * 8;
            short8 v8 = *(const short8*)(vrow + vd0);
            #pragma unroll
            for (int e = 0; e < 8; ++e)
                vt[(vd0 + e) * 72 + tok] = (ushort)v8[e];
        }
    }
    // per-lane global row bases (constant over heads)
    const int myq = wave * 16 + l15;
    const size_t qrow = ((size_t)(wb + (myq >> 3) * 256 + (myq & 7))) * 96;
    size_t krow[4];
    #pragma unroll
    for (int nt = 0; nt < 4; ++nt) {
        int kt2 = nt * 16 + l15;
        krow[nt] = ((size_t)(wb + (kt2 >> 3) * 256 + (kt2 & 7))) * 192;
    }
    // rel-bias indices (head-independent)
    const int qtok0 = wave * 16 + quad * 4;
    int bidx[4][4];
    #pragma unroll
    for (int nt = 0; nt < 4; ++nt) {
        int kt2 = nt * 16 + l15, i2 = kt2 >> 3, j2 = kt2 & 7;
        #pragma unroll
        for (int r = 0; r < 4; ++r) {
            int qt = qtok0 + r, i1 = qt >> 3, j1 = qt & 7;
            bidx[nt][r] = ((i1 - i2 + 7) * 15 + (j1 - j2 + 7)) * 6;
        }
    }
    __syncthreads();   // vt + bias ready

    ushort* ps = (ushort*)(smem + K3_PS) + wave * 1152;   // wave-private [16][72]
    f32x4 accO[6];
    short8 zero8 = {};
    for (int h = 0; h < 6; ++h) {
        short8 aq = zero8;
        if (quad < 2) aq = *(const short8*)(qbuf + qrow + h * 16 + quad * 8);
        f32x4 s[4];
        #pragma unroll
        for (int nt = 0; nt < 4; ++nt) {
            short8 bk8 = zero8;
            if (quad < 2) bk8 = *(const short8*)(kvbuf + krow[nt] + h * 16 + quad * 8);
            f32x4 z = {};
            s[nt] = MFMA(aq, bk8, z);
        }
        #pragma unroll
        for (int nt = 0; nt < 4; ++nt)
            #pragma unroll
            for (int r = 0; r < 4; ++r)
                s[nt][r] += bf2f(biasl[bidx[nt][r] + h]);
        float pr[4][4];
        #pragma unroll
        for (int r = 0; r < 4; ++r) {
            float m = fmaxf(fmaxf(s[0][r], s[1][r]), fmaxf(s[2][r], s[3][r]));
            m = fmaxf(m, __shfl_xor(m, 1)); m = fmaxf(m, __shfl_xor(m, 2));
            m = fmaxf(m, __shfl_xor(m, 4)); m = fmaxf(m, __shfl_xor(m, 8));
            float l = 0.f;
            #pragma unroll
            for (int nt = 0; nt < 4; ++nt) { pr[nt][r] = __expf(s[nt][r] - m); l += pr[nt][r]; }
            l += __shfl_xor(l, 1); l += __shfl_xor(l, 2);
            l += __shfl_xor(l, 4); l += __shfl_xor(l, 8);
            float inv = 1.0f / l;
            #pragma unroll
            for (int nt = 0; nt < 4; ++nt) pr[nt][r] *= inv;
        }
        #pragma unroll
        for (int nt = 0; nt < 4; ++nt)
            #pragma unroll
            for (int r = 0; r < 4; ++r)
                ps[(quad * 4 + r) * 72 + nt * 16 + l15] = f2bf(pr[nt][r]);
        f32x4 o = {};
        #pragma unroll
        for (int k2 = 0; k2 < 2; ++k2) {
            short8 ap  = *(const short8*)(ps + l15 * 72 + k2 * 32 + quad * 8);
            short8 bv8 = *(const short8*)(vt + (h * 16 + l15) * 72 + k2 * 32 + quad * 8);
            o = MFMA(ap, bv8, o);
        }
        accO[h] = o;
    }
    __syncthreads();   // all ps reads done block-wide before obuf overlays region

    ushort* obuf = (ushort*)(smem + K3_PS);               // [64][96]
    #pragma unroll
    for (int h = 0; h < 6; ++h)
        #pragma unroll
        for (int r = 0; r < 4; ++r)
            obuf[(wave * 16 + quad * 4 + r) * 96 + h * 16 + l15] = f2bf(accO[h][r]);
    // own-wave rows -> coalesced 16B stores (wave-private, LDS in-order: no barrier)
    #pragma unroll
    for (int e = 0; e < 3; ++e) {
        int cid = e * 64 + lane;                          // 0..191
        int tr = wave * 16 + cid / 12, c8 = cid % 12;
        short8 o8 = *(const short8*)(obuf + tr * 96 + c8 * 8);
        int tg = wb + (tr >> 3) * 256 + (tr & 7);
        *(short8*)(abuf + (size_t)tg * 96 + c8 * 8) = o8;
    }
}

// ---- K4: out projection, D^T[cout][tok] -> full-line [B,C,H,W] stores ----
__global__ __launch_bounds__(256, 4) void k4_out(
    const ushort* __restrict__ ws, const ushort* __restrict__ abuf,
    const float* __restrict__ bo, float* __restrict__ out)
{
    const int tid = threadIdx.x;
    const int wave = tid >> 6, lane = tid & 63, l15 = lane & 15, quad = lane >> 4;
    const int wtok = blockIdx.x * 64 + wave * 16;         // contiguous global tokens
    const ushort* arow = abuf + (size_t)(wtok + l15) * 96;
    f32x4 acc[6];
    #pragma unroll
    for (int m = 0; m < 6; ++m) acc[m] = {};
    #pragma unroll
    for (int kt = 0; kt < 3; ++kt) {
        short8 bfrag = *(const short8*)(arow + kt * 32 + quad * 8);
        #pragma unroll
        for (int mt = 0; mt < 6; ++mt) {
            short8 a8 = *(const short8*)(ws + WS_O + ((kt * 6 + mt) * 64 + lane) * 8);
            acc[mt] = MFMA(a8, bfrag, acc[mt]);
        }
    }
    const int b = wtok >> 16, rem = wtok & 65535;
    #pragma unroll
    for (int mt = 0; mt < 6; ++mt) {
        float4 bo4 = *(const float4*)(bo + mt * 16 + quad * 4);
        float bv[4] = {bo4.x, bo4.y, bo4.z, bo4.w};
        #pragma unroll
        for (int r = 0; r < 4; ++r) {
            int cout = mt * 16 + quad * 4 + r;
            out[(size_t)(b * 96 + cout) * 65536 + rem + l15] = acc[mt][r] + bv[r];
        }
    }
}

// ======================= FALLBACK (round-2 fused kernel) =======================
#define FB_WQT 0
#define FB_WKT 9216
#define FB_WVT 27648
#define FB_WOT 46080
#define FB_BIAS 55296
#define FB_TOTAL 56646
#define STR_A 104
#define OFF_A 0
#define OFF_K16 13312
#define OFF_VT 25600
#define OFF_PQ 39424
#define OFF_BIAS 50688
#define LDS_BYTES 53392

__global__ void prep_w_fb(const float* __restrict__ Wq, const float* __restrict__ Wk,
                          const float* __restrict__ Wv, const float* __restrict__ Wo,
                          const float* __restrict__ btab, ushort* __restrict__ ws) {
    int idx = blockIdx.x * 256 + threadIdx.x;
    if (idx < FB_WKT) {
        int f = idx >> 9, w = idx & 511, lane = w >> 3, j = w & 7;
        int nt = f / 3, kt = f % 3;
        int n = nt * 16 + (lane & 15), k = kt * 32 + (lane >> 4) * 8 + j;
        ws[idx] = f2bf(Wq[k * 96 + n]);
    } else if (idx < FB_WVT) {
        int t = idx - FB_WKT; int f = t >> 9, w = t & 511, lane = w >> 3, j = w & 7;
        int kt6 = f / 6, nt = f % 6;
        int n = nt * 16 + (lane & 15), k = kt6 * 32 + (lane >> 4) * 8 + j;
        ws[idx] = f2bf(Wk[k * 96 + n]);
    } else if (idx < FB_WOT) {
        int t = idx - FB_WVT; int f = t >> 9, w = t & 511, lane = w >> 3, j = w & 7;
        int kt6 = f / 6, nt = f % 6;
        int n = nt * 16 + (lane & 15), k = kt6 * 32 + (lane >> 4) * 8 + j;
        ws[idx] = f2bf(Wv[k * 96 + n]);
    } else if (idx < FB_BIAS) {
        int t = idx - FB_WOT; int f = t >> 9, w = t & 511, lane = w >> 3, j = w & 7;
        int nt = f / 3, kt = f % 3;
        int n = nt * 16 + (lane & 15), k = kt * 32 + (lane >> 4) * 8 + j;
        ws[idx] = f2bf(Wo[k * 96 + n]);
    } else if (idx < FB_TOTAL) {
        ws[idx] = f2bf(btab[idx - FB_BIAS]);
    }
}

__global__ __launch_bounds__(256, 3) void swin_attn_fb(
    const float* __restrict__ xq, const float* __restrict__ xkv,
    const float* __restrict__ bq, const float* __restrict__ bk,
    const float* __restrict__ bv, const float* __restrict__ bo,
    const ushort* __restrict__ ws, float* __restrict__ out)
{
    __shared__ __align__(16) char smem[LDS_BYTES];
    const int tid = threadIdx.x;
    const int wave = tid >> 6, lane = tid & 63;
    const int l15 = lane & 15, quad = lane >> 4;
    int wid = ((blockIdx.x & 7) << 9) | (blockIdx.x >> 3);
    const int b = wid >> 10;
    const int wh = (wid >> 5) & 31, ww = wid & 31;
    const int h0 = wh * 8, w0 = ww * 8;
    const int mt = wave;
    ushort* A     = (ushort*)(smem + OFF_A);
    ushort* k16   = (ushort*)(smem + OFF_K16);
    ushort* vt    = (ushort*)(smem + OFF_VT);
    ushort* ps    = (ushort*)(smem + OFF_PQ) + wave * (16 * 72);
    ushort* qsc   = (ushort*)(smem + OFF_PQ + 9216) + wave * 256;
    ushort* biasl = (ushort*)(smem + OFF_BIAS);
    float bqr[6], bkr[6], bvr[6], bor[6];
    #pragma unroll
    for (int h = 0; h < 6; ++h) {
        bqr[h] = bq[h * 16 + l15]; bkr[h] = bk[h * 16 + l15];
        bvr[h] = bv[h * 16 + l15]; bor[h] = bo[h * 16 + l15];
    }
    int pc[3], pi[3];
    #pragma unroll
    for (int t = 0; t < 3; ++t) { int p = tid + t * 256; pc[t] = p % 96; pi[t] = p / 96; }
    const float* xkvb = xkv + (size_t)b * 192 * 65536;
    float4 pf[3][2];
    #pragma unroll
    for (int t = 0; t < 3; ++t) {
        const float* g = xkvb + (size_t)pc[t] * 65536 + (h0 + pi[t]) * 256 + w0;
        pf[t][0] = *(const float4*)g; pf[t][1] = *(const float4*)(g + 4);
    }
    for (int i = tid; i < 1350; i += 256) biasl[i] = ws[FB_BIAS + i];
    #pragma unroll
    for (int t = 0; t < 3; ++t) {
        int base = (pi[t] * 8) * STR_A + pc[t];
        A[base] = f2bf(pf[t][0].x); A[base + STR_A] = f2bf(pf[t][0].y);
        A[base + 2 * STR_A] = f2bf(pf[t][0].z); A[base + 3 * STR_A] = f2bf(pf[t][0].w);
        A[base + 4 * STR_A] = f2bf(pf[t][1].x); A[base + 5 * STR_A] = f2bf(pf[t][1].y);
        A[base + 6 * STR_A] = f2bf(pf[t][1].z); A[base + 7 * STR_A] = f2bf(pf[t][1].w);
    }
    __syncthreads();
    float4 pg[3][2];
    #pragma unroll
    for (int t = 0; t < 3; ++t) {
        const float* g = xkvb + (size_t)(96 + pc[t]) * 65536 + (h0 + pi[t]) * 256 + w0;
        pg[t][0] = *(const float4*)g; pg[t][1] = *(const float4*)(g + 4);
    }
    f32x4 accK[6], accV[6];
    #pragma unroll
    for (int n = 0; n < 6; ++n) { accK[n] = {}; accV[n] = {}; }
    const int arow = (mt * 16 + l15) * STR_A + quad * 8;
    #pragma unroll
    for (int kt = 0; kt < 3; ++kt) {
        short8 a = *(const short8*)(A + arow + kt * 32);
        #pragma unroll
        for (int nt = 0; nt < 6; ++nt) {
            short8 bk8 = *(const short8*)(ws + FB_WKT + (((kt * 6) + nt) * 64 + lane) * 8);
            accK[nt] = MFMA(a, bk8, accK[nt]);
            short8 bv8 = *(const short8*)(ws + FB_WVT + (((kt * 6) + nt) * 64 + lane) * 8);
            accV[nt] = MFMA(a, bv8, accV[nt]);
        }
    }
    __syncthreads();
    #pragma unroll
    for (int t = 0; t < 3; ++t) {
        int base = (pi[t] * 8) * STR_A + pc[t];
        A[base] = f2bf(pg[t][0].x); A[base + STR_A] = f2bf(pg[t][0].y);
        A[base + 2 * STR_A] = f2bf(pg[t][0].z); A[base + 3 * STR_A] = f2bf(pg[t][0].w);
        A[base + 4 * STR_A] = f2bf(pg[t][1].x); A[base + 5 * STR_A] = f2bf(pg[t][1].y);
        A[base + 6 * STR_A] = f2bf(pg[t][1].z); A[base + 7 * STR_A] = f2bf(pg[t][1].w);
    }
    __syncthreads();
    const float* xqb = xq + (size_t)b * 96 * 65536;
    #pragma unroll
    for (int t = 0; t < 3; ++t) {
        const float* g = xqb + (size_t)pc[t] * 65536 + (h0 + pi[t]) * 256 + w0;
        pf[t][0] = *(const float4*)g; pf[t][1] = *(const float4*)(g + 4);
    }
    #pragma unroll
    for (int kt = 0; kt < 3; ++kt) {
        short8 a = *(const short8*)(A + arow + kt * 32);
        #pragma unroll
        for (int nt = 0; nt < 6; ++nt) {
            short8 bk8 = *(const short8*)(ws + FB_WKT + ((((3 + kt) * 6) + nt) * 64 + lane) * 8);
            accK[nt] = MFMA(a, bk8, accK[nt]);
            short8 bv8 = *(const short8*)(ws + FB_WVT + ((((3 + kt) * 6) + nt) * 64 + lane) * 8);
            accV[nt] = MFMA(a, bv8, accV[nt]);
        }
    }
    #pragma unroll
    for (int nt = 0; nt < 6; ++nt) {
        ushort* dk = k16 + nt * (64 * 16) + (mt * 16 + quad * 4) * 16 + l15;
        ushort* dv = vt + nt * (16 * 72) + l15 * 72 + (mt * 16 + quad * 4);
        #pragma unroll
        for (int r = 0; r < 4; ++r) {
            dk[r * 16] = f2bf(accK[nt][r] + bkr[nt]);
            dv[r]      = f2bf(accV[nt][r] + bvr[nt]);
        }
    }
    __syncthreads();
    #pragma unroll
    for (int t = 0; t < 3; ++t) {
        int base = (pi[t] * 8) * STR_A + pc[t];
        A[base] = f2bf(pf[t][0].x); A[base + STR_A] = f2bf(pf[t][0].y);
        A[base + 2 * STR_A] = f2bf(pf[t][0].z); A[base + 3 * STR_A] = f2bf(pf[t][0].w);
        A[base + 4 * STR_A] = f2bf(pf[t][1].x); A[base + 5 * STR_A] = f2bf(pf[t][1].y);
        A[base + 6 * STR_A] = f2bf(pf[t][1].z); A[base + 7 * STR_A] = f2bf(pf[t][1].w);
    }
    __syncthreads();
    const int qtok0 = mt * 16 + quad * 4;
    int bidx[4][4];
    #pragma unroll
    for (int nt = 0; nt < 4; ++nt) {
        int kt2 = nt * 16 + l15, i2 = kt2 >> 3, j2 = kt2 & 7;
        #pragma unroll
        for (int r = 0; r < 4; ++r) {
            int qt = qtok0 + r, i1 = qt >> 3, j1 = qt & 7;
            bidx[nt][r] = ((i1 - i2 + 7) * 15 + (j1 - j2 + 7)) * 6;
        }
    }
    f32x4 accO[6];
    short8 zero8 = {};
    for (int h = 0; h < 6; ++h) {
        f32x4 qa = {};
        #pragma unroll
        for (int kt = 0; kt < 3; ++kt) {
            short8 a  = *(const short8*)(A + arow + kt * 32);
            short8 bb = *(const short8*)(ws + FB_WQT + ((h * 3 + kt) * 64 + lane) * 8);
            qa = MFMA(a, bb, qa);
        }
        #pragma unroll
        for (int r = 0; r < 4; ++r)
            qsc[(quad * 4 + r) * 16 + l15] = f2bf((qa[r] + bqr[h]) * 0.25f);
        short8 aq = zero8;
        if (quad < 2) aq = *(const short8*)(qsc + l15 * 16 + quad * 8);
        f32x4 s[4];
        #pragma unroll
        for (int nt = 0; nt < 4; ++nt) {
            short8 bk8 = zero8;
            if (quad < 2) bk8 = *(const short8*)(k16 + h * (64 * 16) + (nt * 16 + l15) * 16 + quad * 8);
            f32x4 z = {};
            s[nt] = MFMA(aq, bk8, z);
        }
        #pragma unroll
        for (int nt = 0; nt < 4; ++nt)
            #pragma unroll
            for (int r = 0; r < 4; ++r)
                s[nt][r] += bf2f(biasl[bidx[nt][r] + h]);
        float pr[4][4];
        #pragma unroll
        for (int r = 0; r < 4; ++r) {
            float m = fmaxf(fmaxf(s[0][r], s[1][r]), fmaxf(s[2][r], s[3][r]));
            m = fmaxf(m, __shfl_xor(m, 1)); m = fmaxf(m, __shfl_xor(m, 2));
            m = fmaxf(m, __shfl_xor(m, 4)); m = fmaxf(m, __shfl_xor(m, 8));
            float l = 0.f;
            #pragma unroll
            for (int nt = 0; nt < 4; ++nt) { pr[nt][r] = __expf(s[nt][r] - m); l += pr[nt][r]; }
            l += __shfl_xor(l, 1); l += __shfl_xor(l, 2);
            l += __shfl_xor(l, 4); l += __shfl_xor(l, 8);
            float inv = 1.0f / l;
            #pragma unroll
            for (int nt = 0; nt < 4; ++nt) pr[nt][r] *= inv;
        }
        #pragma unroll
        for (int nt = 0; nt < 4; ++nt)
            #pragma unroll
            for (int r = 0; r < 4; ++r)
                ps[(quad * 4 + r) * 72 + nt * 16 + l15] = f2bf(pr[nt][r]);
        f32x4 o = {};
        #pragma unroll
        for (int k2 = 0; k2 < 2; ++k2) {
            short8 ap  = *(const short8*)(ps + l15 * 72 + k2 * 32 + quad * 8);
            short8 bv8 = *(const short8*)(vt + h * (16 * 72) + l15 * 72 + k2 * 32 + quad * 8);
            o = MFMA(ap, bv8, o);
        }
        accO[h] = o;
    }
    __syncthreads();
    ushort* obuf = A;
    #pragma unroll
    for (int h = 0; h < 6; ++h)
        #pragma unroll
        for (int r = 0; r < 4; ++r)
            obuf[(mt * 16 + quad * 4 + r) * STR_A + h * 16 + l15] = f2bf(accO[h][r]);
    {
        int t0 = mt * 16 + quad * 4;
        int i = t0 >> 3, j0 = t0 & 7;
        #pragma unroll
        for (int nt = 0; nt < 6; ++nt) {
            f32x4 acc = {};
            #pragma unroll
            for (int kt = 0; kt < 3; ++kt) {
                short8 a  = *(const short8*)(obuf + arow + kt * 32);
                short8 bb = *(const short8*)(ws + FB_WOT + ((nt * 3 + kt) * 64 + lane) * 8);
                acc = MFMA(a, bb, acc);
            }
            int cout = nt * 16 + l15;
            float4 v4 = make_float4(acc[0] + bor[nt], acc[1] + bor[nt], acc[2] + bor[nt], acc[3] + bor[nt]);
            float* dst = out + (size_t)(b * 96 + cout) * 65536 + (h0 + i) * 256 + w0 + j0;
            *(float4*)dst = v4;
        }
    }
}

extern "C" void kernel_launch(void* const* d_in, const int* in_sizes, int n_in,
                              void* d_out, int out_size, void* d_ws, size_t ws_size,
                              hipStream_t stream) {
    const float* xq   = (const float*)d_in[0];
    const float* xkv  = (const float*)d_in[1];
    const float* Wq   = (const float*)d_in[2];
    const float* bq   = (const float*)d_in[3];
    const float* Wk   = (const float*)d_in[4];
    const float* bk   = (const float*)d_in[5];
    const float* Wv   = (const float*)d_in[6];
    const float* bv   = (const float*)d_in[7];
    const float* btab = (const float*)d_in[8];
    const float* Wo   = (const float*)d_in[9];
    const float* bo   = (const float*)d_in[10];
    ushort* ws = (ushort*)d_ws;
    float* out = (float*)d_out;

    if (ws_size >= NEED_BYTES) {
        ushort* qbuf  = ws + QBUF_OFF;
        ushort* kvbuf = ws + KVBUF_OFF;
        ushort* abuf  = ws + ABUF_OFF;
        hipLaunchKernelGGL(prep_w, dim3(222), dim3(256), 0, stream, Wq, Wk, Wv, Wo, btab, ws);
        hipLaunchKernelGGL(k2_proj, dim3(8192), dim3(256), 0, stream,
                           xq, xkv, bq, bk, bv, ws, qbuf, kvbuf);
        hipLaunchKernelGGL(k3_attn, dim3(4096), dim3(256), 0, stream, ws, qbuf, kvbuf, abuf);
        hipLaunchKernelGGL(k4_out, dim3(4096), dim3(256), 0, stream, ws, abuf, bo, out);
    } else {
        hipLaunchKernelGGL(prep_w_fb, dim3(222), dim3(256), 0, stream, Wq, Wk, Wv, Wo, btab, ws);
        hipLaunchKernelGGL(swin_attn_fb, dim3(4096), dim3(256), 0, stream,
                           xq, xkv, bq, bk, bv, bo, ws, out);
    }
}